// Round 1
// baseline (814.088 us; speedup 1.0000x reference)
//
#include <hip/hip_runtime.h>
#include <hip/hip_bf16.h>
#include <cstddef>

#define BB 8
#define CC 512
#define NN 4096
#define CQ 64
#define MQ 32   // Q-rows per attn block (halved: zero extra FLOPs, halves regs -> 4 blocks/CU)
#define NJ 64   // j-tile

typedef short bf16x8 __attribute__((ext_vector_type(8)));
typedef float f32x4  __attribute__((ext_vector_type(4)));

// fp32 -> bf16 bits, round-to-nearest-even
static __device__ __forceinline__ unsigned bf16_bits(float f){
  unsigned u = __float_as_uint(f);
  u += 0x7fffu + ((u >> 16) & 1u);
  return u >> 16;
}
static __device__ __forceinline__ unsigned pack2bf(float lo, float hi){
  return bf16_bits(lo) | (bf16_bits(hi) << 16);
}

// ---- weights fp32 -> bf16 (Wqk packed: rows 0..63 = Wq, 64..127 = Wk) ----
__global__ __launch_bounds__(256) void cvt_w_kernel(
    const float* __restrict__ Wq, const float* __restrict__ Wk,
    const float* __restrict__ Wv,
    short* __restrict__ Wqkbf, short* __restrict__ Wvbf){
  const int i = blockIdx.x*256 + threadIdx.x;
  if (i < CQ*CC){
    Wqkbf[i]         = (short)bf16_bits(Wq[i]);
    Wqkbf[CQ*CC + i] = (short)bf16_bits(Wk[i]);
  }
  Wvbf[i] = (short)bf16_bits(Wv[i]);
}

// ---- x fp32 [b][c][n] -> xT bf16 [b][n][c] via LDS 64x64 tile ----
__global__ __launch_bounds__(256) void cvt_x_kernel(
    const float* __restrict__ x, short* __restrict__ xT){
  __shared__ float lds[64*67];
  const int tid = threadIdx.x;
  const int n0 = blockIdx.x*64, c0 = blockIdx.y*64, b = blockIdx.z;
  const int nl = tid & 63, cw = tid >> 6;
  const float* xp = x + ((size_t)b*CC + c0)*NN + n0;
#pragma unroll
  for (int i=0;i<16;++i){
    const int cl = cw*16 + i;
    lds[nl*67 + cl] = xp[(size_t)cl*NN + nl];
  }
  __syncthreads();
  short* xTp = xT + ((size_t)b*NN + n0)*CC + c0;
#pragma unroll
  for (int p=0;p<2;++p){
    const int nl2 = (tid>>3) + p*32;
    const int c8 = (tid&7)*8;
    const float* r = &lds[nl2*67 + c8];
    uint4 v;
    v.x = pack2bf(r[0], r[1]);
    v.y = pack2bf(r[2], r[3]);
    v.z = pack2bf(r[4], r[5]);
    v.w = pack2bf(r[6], r[7]);
    *(uint4*)&xTp[(size_t)nl2*CC + c8] = v;
  }
}

// ---- Q,K projection via MFMA: D[n][o] = xT . Wqk^T;  Qbf/Kbf layout [b][n][64] ----
// Q is pre-scaled by log2(e) so attn can use raw v_exp_f32 (2^x).
__global__ __launch_bounds__(256) void proj_qk_mfma(
    const short* __restrict__ xT, const short* __restrict__ Wqkbf,
    const float* __restrict__ bq, const float* __restrict__ bk,
    short* __restrict__ Qbf, short* __restrict__ Kbf){
  const int tid  = threadIdx.x;
  const int lane = tid & 63;
  const int w    = tid >> 6;
  const int iq   = lane & 15;
  const int q    = lane >> 4;
  const int b    = blockIdx.z;
  const int n0w  = blockIdx.x*128 + w*32;

  f32x4 acc[2][8];
#pragma unroll
  for (int ns=0;ns<2;++ns)
#pragma unroll
    for (int os=0;os<8;++os) acc[ns][os] = (f32x4){0.f,0.f,0.f,0.f};

  const short* Abase = xT + ((size_t)b*NN + n0w + iq)*CC + q*8;
  const short* Bbase = Wqkbf + (size_t)iq*CC + q*8;

  for (int ks=0; ks<16; ++ks){
    const int k = ks*32;
    bf16x8 af[2], bf[8];
#pragma unroll
    for (int ns=0;ns<2;++ns) af[ns] = *(const bf16x8*)(Abase + (size_t)ns*16*CC + k);
#pragma unroll
    for (int os=0;os<8;++os) bf[os] = *(const bf16x8*)(Bbase + (size_t)os*16*CC + k);
#pragma unroll
    for (int ns=0;ns<2;++ns)
#pragma unroll
      for (int os=0;os<8;++os)
        acc[ns][os] = __builtin_amdgcn_mfma_f32_16x16x32_bf16(af[ns], bf[os], acc[ns][os], 0,0,0);
  }
#pragma unroll
  for (int ns=0;ns<2;++ns){
#pragma unroll
    for (int os=0;os<8;++os){
      const int o = (os&4) ? ((os-4)*16 + iq) : (os*16 + iq);
      const float bias = (os<4) ? bq[o] : bk[o];
      short* dst = (os<4) ? Qbf : Kbf;
#pragma unroll
      for (int r=0;r<4;++r){
        const int n = n0w + ns*16 + q*4 + r;
        float v = acc[ns][os][r] + bias;
        if (os < 4) v *= 1.44269504088896f;  // fold log2(e) into Q
        dst[((size_t)b*NN + n)*CQ + o] = (short)bf16_bits(v);
      }
    }
  }
}

// ---- V projection via MFMA: D[c][n] = Wv . x;  Vbf layout [b][c][n] ----
__global__ __launch_bounds__(256) void proj_v_mfma(
    const short* __restrict__ xT, const short* __restrict__ Wvbf,
    const float* __restrict__ bv, short* __restrict__ Vbf){
  const int tid  = threadIdx.x;
  const int lane = tid & 63;
  const int w    = tid >> 6;
  const int iq   = lane & 15;
  const int q    = lane >> 4;
  const int b    = blockIdx.z;
  const int c0w  = blockIdx.y*128 + (w&1)*64;
  const int n0w  = blockIdx.x*64 + (w>>1)*32;

  f32x4 acc[4][2];
#pragma unroll
  for (int cs=0;cs<4;++cs)
#pragma unroll
    for (int ns=0;ns<2;++ns) acc[cs][ns] = (f32x4){0.f,0.f,0.f,0.f};

  const short* Abase = Wvbf + (size_t)(c0w + iq)*CC + q*8;
  const short* Bbase = xT + ((size_t)b*NN + n0w + iq)*CC + q*8;

  for (int ks=0; ks<16; ++ks){
    const int k = ks*32;
    bf16x8 af[4], bf[2];
#pragma unroll
    for (int cs=0;cs<4;++cs) af[cs] = *(const bf16x8*)(Abase + (size_t)cs*16*CC + k);
#pragma unroll
    for (int ns=0;ns<2;++ns) bf[ns] = *(const bf16x8*)(Bbase + (size_t)ns*16*CC + k);
#pragma unroll
    for (int cs=0;cs<4;++cs)
#pragma unroll
      for (int ns=0;ns<2;++ns)
        acc[cs][ns] = __builtin_amdgcn_mfma_f32_16x16x32_bf16(af[cs], bf[ns], acc[cs][ns], 0,0,0);
  }
#pragma unroll
  for (int cs=0;cs<4;++cs){
#pragma unroll
    for (int r=0;r<4;++r){
      const int c = c0w + cs*16 + q*4 + r;
      const float bias = bv[c];
#pragma unroll
      for (int ns=0;ns<2;++ns){
        const int n = n0w + ns*16 + iq;
        Vbf[((size_t)b*CC + c)*NN + n] = (short)bf16_bits(acc[cs][ns][r] + bias);
      }
    }
  }
}

// ---- MFMA flash attention, pipelined ----
// Grid 2048: bid&7 = batch (XCD swizzle), (bid>>3)&1 = c-half (256 ch), bid>>4 = i-tile (MQ=32).
// P tile LDS layout: 16-B chunk per (j-octet jo 0..7, i 0..31): dword off (jo*32+i)*4.
// Double-buffered; one lgkmcnt-only barrier per jt (global prefetches stay in flight).
// MQ=32 keeps register live-set <=128 -> 4 blocks/CU (vs 2 at MQ=64).
__global__ __launch_bounds__(256, 4) void attn_mfma_kernel(
    const short* __restrict__ Qbf, const short* __restrict__ Kbf,
    const short* __restrict__ Vbf, const float* __restrict__ x,
    const float* __restrict__ gamma, float* __restrict__ out){
  __shared__ unsigned plds[2][1024];
  __shared__ float lsum[4][MQ];

  const int tid  = threadIdx.x;
  const int lane = tid & 63;
  const int w    = tid >> 6;
  const int iq   = lane & 15;
  const int q    = lane >> 4;
  const int bid  = blockIdx.x;
  const int b    = bid & 7;
  const int ch   = ((bid >> 3) & 1) * 256;
  const int i0   = (bid >> 4) * MQ;

  // Q B-frags (persistent), pre-scaled by log2(e) in proj
  bf16x8 qb[2][2];
#pragma unroll
  for (int s=0;s<2;++s){
    const short* qp = Qbf + ((size_t)b*NN + i0 + s*16 + iq)*CQ + q*8;
    qb[s][0] = *(const bf16x8*)qp;
    qb[s][1] = *(const bf16x8*)(qp + 32);
  }

  f32x4 acc[4][2];
#pragma unroll
  for (int cs=0;cs<4;++cs)
#pragma unroll
    for (int s=0;s<2;++s) acc[cs][s] = (f32x4){0.f,0.f,0.f,0.f};
  float lpart[2] = {0.f,0.f};

  const short* Kbase = Kbf + ((size_t)b*NN + w*16 + iq)*CQ + q*8;        // A[m=j][k=o]
  const short* Vbase = Vbf + ((size_t)b*CC + ch + w*64 + iq)*NN + q*8;   // A[m=c][k=j]

  // LDS dword offsets: producer writes chunk jo=w*2+(q>>1), consumer reads jo=q (+4 for ks=1)
  const int woff  = (w*2 + (q>>1))*128 + iq*4 + (q&1)*2;   // + s*64
  const int roff0 = q*128 + iq*4;                          // + s*64 (+512 for ks=1)

  // K prefetch (double-buffered in regs)
  bf16x8 ka0 = *(const bf16x8*)Kbase;
  bf16x8 ka1 = *(const bf16x8*)(Kbase + 32);

#pragma unroll 2
  for (int jt=0; jt<NN/NJ; ++jt){
    const int buf = jt & 1;
    const int j0 = jt*NJ;

    // ---- issue V loads for THIS jt (consumed after barrier, ~350 cyc later) ----
    bf16x8 va[4][2];
    const short* vp = Vbase + j0;
#pragma unroll
    for (int cs=0;cs<4;++cs){
      const short* vrow = vp + (size_t)cs*16*NN;
      va[cs][0] = *(const bf16x8*)vrow;
      va[cs][1] = *(const bf16x8*)(vrow + 32);
    }
    // ---- prefetch K for jt+1 (reads past Kbf stay inside workspace; unused) ----
    const short* kp = Kbase + (size_t)(j0 + NJ)*CQ;
    bf16x8 kn0 = *(const bf16x8*)kp;
    bf16x8 kn1 = *(const bf16x8*)(kp + 32);

    // ---- S^T = K . Q^T  (Q pre-scaled by log2e) ----
    f32x4 sf[2];
#pragma unroll
    for (int s=0;s<2;++s){
      sf[s] = __builtin_amdgcn_mfma_f32_16x16x32_bf16(ka0, qb[s][0], (f32x4){0.f,0.f,0.f,0.f}, 0,0,0);
      sf[s] = __builtin_amdgcn_mfma_f32_16x16x32_bf16(ka1, qb[s][1], sf[s], 0,0,0);
    }
    // ---- exp2, l partial, pack to LDS (conflict-free chunk layout) ----
#pragma unroll
    for (int s=0;s<2;++s){
      const float p0 = __builtin_amdgcn_exp2f(sf[s][0]);
      const float p1 = __builtin_amdgcn_exp2f(sf[s][1]);
      const float p2 = __builtin_amdgcn_exp2f(sf[s][2]);
      const float p3 = __builtin_amdgcn_exp2f(sf[s][3]);
      lpart[s] += (p0+p1) + (p2+p3);
      plds[buf][woff + s*64]     = pack2bf(p0, p1);
      plds[buf][woff + s*64 + 1] = pack2bf(p2, p3);
    }
    // ---- LDS-only barrier: wait lgkmcnt(0), leave vmcnt in flight ----
    __builtin_amdgcn_s_waitcnt(0xc07f);
    __builtin_amdgcn_s_barrier();

    // ---- PV: B-frags from LDS, A = V fragments (already in flight) ----
#pragma unroll
    for (int s=0;s<2;++s){
      const bf16x8 pb0 = *(const bf16x8*)&plds[buf][roff0 + s*64];
      const bf16x8 pb1 = *(const bf16x8*)&plds[buf][roff0 + s*64 + 512];
#pragma unroll
      for (int cs=0;cs<4;++cs){
        acc[cs][s] = __builtin_amdgcn_mfma_f32_16x16x32_bf16(va[cs][0], pb0, acc[cs][s], 0,0,0);
        acc[cs][s] = __builtin_amdgcn_mfma_f32_16x16x32_bf16(va[cs][1], pb1, acc[cs][s], 0,0,0);
      }
    }
    ka0 = kn0; ka1 = kn1;
  }

  // ---- l reduction ----
#pragma unroll
  for (int s=0;s<2;++s){
    lpart[s] += __shfl_xor(lpart[s], 16, 64);
    lpart[s] += __shfl_xor(lpart[s], 32, 64);
  }
  __syncthreads();
  if (q == 0){
#pragma unroll
    for (int s=0;s<2;++s) lsum[w][s*16 + iq] = lpart[s];
  }
  __syncthreads();
  float linv[2];
#pragma unroll
  for (int s=0;s<2;++s){
    const int i = s*16 + iq;
    linv[s] = 1.0f / (lsum[0][i] + lsum[1][i] + lsum[2][i] + lsum[3][i]);
  }

  const float gam = gamma[0];
#pragma unroll
  for (int cs=0;cs<4;++cs){
#pragma unroll
    for (int s=0;s<2;++s){
      const int cb = ch + w*64 + cs*16 + q*4;
      const int i  = i0 + s*16 + iq;
#pragma unroll
      for (int r=0;r<4;++r){
        const size_t idx = ((size_t)b*CC + cb + r)*NN + i;
        out[idx] = fmaf(gam, acc[cs][s][r]*linv[s], x[idx]);
      }
    }
  }
}

extern "C" void kernel_launch(void* const* d_in, const int* in_sizes, int n_in,
                              void* d_out, int out_size, void* d_ws, size_t ws_size,
                              hipStream_t stream){
  const float* x     = (const float*)d_in[0];
  const float* Wq    = (const float*)d_in[1];
  const float* bq    = (const float*)d_in[2];
  const float* Wk    = (const float*)d_in[3];
  const float* bk    = (const float*)d_in[4];
  const float* Wv    = (const float*)d_in[5];
  const float* bv    = (const float*)d_in[6];
  const float* gamma = (const float*)d_in[7];
  float* out = (float*)d_out;

  // workspace: xT bf16 [8][4096][512] 33.6MB; Qbf/Kbf bf16 [8][4096][64] 4.2MB each;
  // Vbf bf16 [8][512][4096] 33.6MB; Wqkbf [128][512] 128KB; Wvbf [512][512] 512KB. ~76 MB
  short* xTbf = (short*)d_ws;
  short* Qbf  = xTbf + (size_t)BB*NN*CC;
  short* Kbf  = Qbf  + (size_t)BB*NN*CQ;
  short* Vbf  = Kbf  + (size_t)BB*NN*CQ;
  short* Wqkbf= Vbf  + (size_t)BB*CC*NN;
  short* Wvbf = Wqkbf + (size_t)2*CQ*CC;

  cvt_w_kernel<<<dim3(CC*CC/256), 256, 0, stream>>>(Wq, Wk, Wv, Wqkbf, Wvbf);
  cvt_x_kernel<<<dim3(NN/64, CC/64, BB), 256, 0, stream>>>(x, xTbf);
  proj_qk_mfma<<<dim3(NN/128, 1, BB), 256, 0, stream>>>(xTbf, Wqkbf, bq, bk, Qbf, Kbf);
  proj_v_mfma<<<dim3(NN/64, CC/128, BB), 256, 0, stream>>>(xTbf, Wvbf, bv, Vbf);
  attn_mfma_kernel<<<dim3(BB*NN*2/MQ), 256, 0, stream>>>(Qbf, Kbf, Vbf, x, gamma, out);
}

// Round 2
// 531.261 us; speedup vs baseline: 1.5324x; 1.5324x over previous
//
#include <hip/hip_runtime.h>
#include <hip/hip_bf16.h>
#include <cstddef>

#define BB 8
#define CC 512
#define NN 4096
#define CQ 64
#define MQ 64   // Q-rows per attn block
#define NJ 64   // j-tile

typedef short bf16x8 __attribute__((ext_vector_type(8)));
typedef float f32x4  __attribute__((ext_vector_type(4)));

// fp32 -> bf16 bits, round-to-nearest-even
static __device__ __forceinline__ unsigned bf16_bits(float f){
  unsigned u = __float_as_uint(f);
  u += 0x7fffu + ((u >> 16) & 1u);
  return u >> 16;
}
static __device__ __forceinline__ unsigned pack2bf(float lo, float hi){
  return bf16_bits(lo) | (bf16_bits(hi) << 16);
}

// ---- weights fp32 -> bf16 (Wqk packed: rows 0..63 = Wq, 64..127 = Wk) ----
__global__ __launch_bounds__(256) void cvt_w_kernel(
    const float* __restrict__ Wq, const float* __restrict__ Wk,
    const float* __restrict__ Wv,
    short* __restrict__ Wqkbf, short* __restrict__ Wvbf){
  const int i = blockIdx.x*256 + threadIdx.x;
  if (i < CQ*CC){
    Wqkbf[i]         = (short)bf16_bits(Wq[i]);
    Wqkbf[CQ*CC + i] = (short)bf16_bits(Wk[i]);
  }
  Wvbf[i] = (short)bf16_bits(Wv[i]);
}

// ---- x fp32 [b][c][n] -> xT bf16 [b][n][c] via LDS 64x64 tile ----
__global__ __launch_bounds__(256) void cvt_x_kernel(
    const float* __restrict__ x, short* __restrict__ xT){
  __shared__ float lds[64*67];
  const int tid = threadIdx.x;
  const int n0 = blockIdx.x*64, c0 = blockIdx.y*64, b = blockIdx.z;
  const int nl = tid & 63, cw = tid >> 6;
  const float* xp = x + ((size_t)b*CC + c0)*NN + n0;
#pragma unroll
  for (int i=0;i<16;++i){
    const int cl = cw*16 + i;
    lds[nl*67 + cl] = xp[(size_t)cl*NN + nl];
  }
  __syncthreads();
  short* xTp = xT + ((size_t)b*NN + n0)*CC + c0;
#pragma unroll
  for (int p=0;p<2;++p){
    const int nl2 = (tid>>3) + p*32;
    const int c8 = (tid&7)*8;
    const float* r = &lds[nl2*67 + c8];
    uint4 v;
    v.x = pack2bf(r[0], r[1]);
    v.y = pack2bf(r[2], r[3]);
    v.z = pack2bf(r[4], r[5]);
    v.w = pack2bf(r[6], r[7]);
    *(uint4*)&xTp[(size_t)nl2*CC + c8] = v;
  }
}

// ---- Q,K projection via MFMA: D[n][o] = xT . Wqk^T;  Qbf/Kbf layout [b][n][64] ----
// Q is pre-scaled by log2(e) so attn can use raw v_exp_f32 (2^x).
__global__ __launch_bounds__(256) void proj_qk_mfma(
    const short* __restrict__ xT, const short* __restrict__ Wqkbf,
    const float* __restrict__ bq, const float* __restrict__ bk,
    short* __restrict__ Qbf, short* __restrict__ Kbf){
  const int tid  = threadIdx.x;
  const int lane = tid & 63;
  const int w    = tid >> 6;
  const int iq   = lane & 15;
  const int q    = lane >> 4;
  const int b    = blockIdx.z;
  const int n0w  = blockIdx.x*128 + w*32;

  f32x4 acc[2][8];
#pragma unroll
  for (int ns=0;ns<2;++ns)
#pragma unroll
    for (int os=0;os<8;++os) acc[ns][os] = (f32x4){0.f,0.f,0.f,0.f};

  const short* Abase = xT + ((size_t)b*NN + n0w + iq)*CC + q*8;
  const short* Bbase = Wqkbf + (size_t)iq*CC + q*8;

  for (int ks=0; ks<16; ++ks){
    const int k = ks*32;
    bf16x8 af[2], bf[8];
#pragma unroll
    for (int ns=0;ns<2;++ns) af[ns] = *(const bf16x8*)(Abase + (size_t)ns*16*CC + k);
#pragma unroll
    for (int os=0;os<8;++os) bf[os] = *(const bf16x8*)(Bbase + (size_t)os*16*CC + k);
#pragma unroll
    for (int ns=0;ns<2;++ns)
#pragma unroll
      for (int os=0;os<8;++os)
        acc[ns][os] = __builtin_amdgcn_mfma_f32_16x16x32_bf16(af[ns], bf[os], acc[ns][os], 0,0,0);
  }
#pragma unroll
  for (int ns=0;ns<2;++ns){
#pragma unroll
    for (int os=0;os<8;++os){
      const int o = (os&4) ? ((os-4)*16 + iq) : (os*16 + iq);
      const float bias = (os<4) ? bq[o] : bk[o];
      short* dst = (os<4) ? Qbf : Kbf;
#pragma unroll
      for (int r=0;r<4;++r){
        const int n = n0w + ns*16 + q*4 + r;
        float v = acc[ns][os][r] + bias;
        if (os < 4) v *= 1.44269504088896f;  // fold log2(e) into Q
        dst[((size_t)b*NN + n)*CQ + o] = (short)bf16_bits(v);
      }
    }
  }
}

// ---- V projection via MFMA: D[c][n] = Wv . x;  Vbf layout [b][c][n] ----
__global__ __launch_bounds__(256) void proj_v_mfma(
    const short* __restrict__ xT, const short* __restrict__ Wvbf,
    const float* __restrict__ bv, short* __restrict__ Vbf){
  const int tid  = threadIdx.x;
  const int lane = tid & 63;
  const int w    = tid >> 6;
  const int iq   = lane & 15;
  const int q    = lane >> 4;
  const int b    = blockIdx.z;
  const int c0w  = blockIdx.y*128 + (w&1)*64;
  const int n0w  = blockIdx.x*64 + (w>>1)*32;

  f32x4 acc[4][2];
#pragma unroll
  for (int cs=0;cs<4;++cs)
#pragma unroll
    for (int ns=0;ns<2;++ns) acc[cs][ns] = (f32x4){0.f,0.f,0.f,0.f};

  const short* Abase = Wvbf + (size_t)(c0w + iq)*CC + q*8;
  const short* Bbase = xT + ((size_t)b*NN + n0w + iq)*CC + q*8;

  for (int ks=0; ks<16; ++ks){
    const int k = ks*32;
    bf16x8 af[4], bf[2];
#pragma unroll
    for (int cs=0;cs<4;++cs) af[cs] = *(const bf16x8*)(Abase + (size_t)cs*16*CC + k);
#pragma unroll
    for (int ns=0;ns<2;++ns) bf[ns] = *(const bf16x8*)(Bbase + (size_t)ns*16*CC + k);
#pragma unroll
    for (int cs=0;cs<4;++cs)
#pragma unroll
      for (int ns=0;ns<2;++ns)
        acc[cs][ns] = __builtin_amdgcn_mfma_f32_16x16x32_bf16(af[cs], bf[ns], acc[cs][ns], 0,0,0);
  }
#pragma unroll
  for (int cs=0;cs<4;++cs){
#pragma unroll
    for (int r=0;r<4;++r){
      const int c = c0w + cs*16 + q*4 + r;
      const float bias = bv[c];
#pragma unroll
      for (int ns=0;ns<2;++ns){
        const int n = n0w + ns*16 + iq;
        Vbf[((size_t)b*CC + c)*NN + n] = (short)bf16_bits(acc[cs][ns][r] + bias);
      }
    }
  }
}

// ---- MFMA flash attention, pipelined ----
// Grid 1024: bid&7 = batch (XCD swizzle -> each XCD's L2 holds one batch's K/V),
// (bid>>3)&1 = c-half (256 ch), bid>>4 = i-tile (MQ=64).
// P tile LDS layout: 16-B chunk per (j-octet jo 0..7, i 0..63): dword off (jo*64+i)*4.
// Double-buffered LDS; one lgkmcnt-only barrier per jt (global prefetches stay in flight).
// BOTH K and V are register-double-buffered one full jt ahead: PV never waits on L2.
__global__ __launch_bounds__(256, 2) void attn_mfma_kernel(
    const short* __restrict__ Qbf, const short* __restrict__ Kbf,
    const short* __restrict__ Vbf, const float* __restrict__ x,
    const float* __restrict__ gamma, float* __restrict__ out){
  __shared__ unsigned plds[2][2048];
  __shared__ float lsum[4][MQ];

  const int tid  = threadIdx.x;
  const int lane = tid & 63;
  const int w    = tid >> 6;
  const int iq   = lane & 15;
  const int q    = lane >> 4;
  const int bid  = blockIdx.x;
  const int b    = bid & 7;
  const int ch   = ((bid >> 3) & 1) * 256;
  const int i0   = (bid >> 4) * MQ;

  // Q B-frags (persistent), pre-scaled by log2(e) in proj
  bf16x8 qb[4][2];
#pragma unroll
  for (int s=0;s<4;++s){
    const short* qp = Qbf + ((size_t)b*NN + i0 + s*16 + iq)*CQ + q*8;
    qb[s][0] = *(const bf16x8*)qp;
    qb[s][1] = *(const bf16x8*)(qp + 32);
  }

  f32x4 acc[4][4];
#pragma unroll
  for (int cs=0;cs<4;++cs)
#pragma unroll
    for (int s=0;s<4;++s) acc[cs][s] = (f32x4){0.f,0.f,0.f,0.f};
  float lpart[4] = {0.f,0.f,0.f,0.f};

  const short* Kbase = Kbf + ((size_t)b*NN + w*16 + iq)*CQ + q*8;        // A[m=j][k=o]
  const short* Vbase = Vbf + ((size_t)b*CC + ch + w*64 + iq)*NN + q*8;   // A[m=c][k=j]

  // LDS dword offsets: producer writes chunk jo=w*2+(q>>1), consumer reads jo=q+4*ks
  const int woff  = (w*2 + (q>>1))*256 + iq*4 + (q&1)*2;   // + s*64
  const int roff0 = q*256 + iq*4;                          // + s*64 (+1024 for ks=1)

  // K + V prefetch for jt=0 (both double-buffered in regs, one full jt ahead)
  bf16x8 ka0 = *(const bf16x8*)Kbase;
  bf16x8 ka1 = *(const bf16x8*)(Kbase + 32);
  bf16x8 vc[4][2];
#pragma unroll
  for (int cs=0;cs<4;++cs){
    const short* vrow = Vbase + (size_t)cs*16*NN;
    vc[cs][0] = *(const bf16x8*)vrow;
    vc[cs][1] = *(const bf16x8*)(vrow + 32);
  }

#pragma unroll 2
  for (int jt=0; jt<NN/NJ; ++jt){
    const int buf = jt & 1;
    const int j0 = jt*NJ;

    // ---- issue V loads for jt+1 (consumed NEXT iteration, ~full jt of slack;
    //      overreads past Vbf end land in Wqkbf region, still in workspace, unused) ----
    bf16x8 vn[4][2];
    const short* vp = Vbase + j0 + NJ;
#pragma unroll
    for (int cs=0;cs<4;++cs){
      const short* vrow = vp + (size_t)cs*16*NN;
      vn[cs][0] = *(const bf16x8*)vrow;
      vn[cs][1] = *(const bf16x8*)(vrow + 32);
    }
    // ---- prefetch K for jt+1 (reads past Kbf stay inside workspace; unused) ----
    const short* kp = Kbase + (size_t)(j0 + NJ)*CQ;
    bf16x8 kn0 = *(const bf16x8*)kp;
    bf16x8 kn1 = *(const bf16x8*)(kp + 32);

    // ---- S^T = K . Q^T  (Q pre-scaled by log2e) ----
    f32x4 sf[4];
#pragma unroll
    for (int s=0;s<4;++s){
      sf[s] = __builtin_amdgcn_mfma_f32_16x16x32_bf16(ka0, qb[s][0], (f32x4){0.f,0.f,0.f,0.f}, 0,0,0);
      sf[s] = __builtin_amdgcn_mfma_f32_16x16x32_bf16(ka1, qb[s][1], sf[s], 0,0,0);
    }
    // ---- exp2, l partial, pack to LDS (conflict-free chunk layout, b64 writes) ----
#pragma unroll
    for (int s=0;s<4;++s){
      const float p0 = __builtin_amdgcn_exp2f(sf[s][0]);
      const float p1 = __builtin_amdgcn_exp2f(sf[s][1]);
      const float p2 = __builtin_amdgcn_exp2f(sf[s][2]);
      const float p3 = __builtin_amdgcn_exp2f(sf[s][3]);
      lpart[s] += (p0+p1) + (p2+p3);
      uint2 pw;
      pw.x = pack2bf(p0, p1);
      pw.y = pack2bf(p2, p3);
      *(uint2*)&plds[buf][woff + s*64] = pw;   // 8B-aligned -> ds_write_b64
    }
    // ---- LDS-only barrier: wait lgkmcnt(0), leave vmcnt in flight ----
    __builtin_amdgcn_s_waitcnt(0xc07f);
    __builtin_amdgcn_s_barrier();

    // ---- PV: B-frags from LDS, A = V fragments loaded LAST iteration (in regs) ----
#pragma unroll
    for (int s=0;s<4;++s){
      const bf16x8 pb0 = *(const bf16x8*)&plds[buf][roff0 + s*64];
      const bf16x8 pb1 = *(const bf16x8*)&plds[buf][roff0 + s*64 + 1024];
#pragma unroll
      for (int cs=0;cs<4;++cs){
        acc[cs][s] = __builtin_amdgcn_mfma_f32_16x16x32_bf16(vc[cs][0], pb0, acc[cs][s], 0,0,0);
        acc[cs][s] = __builtin_amdgcn_mfma_f32_16x16x32_bf16(vc[cs][1], pb1, acc[cs][s], 0,0,0);
      }
    }
    // ---- rotate double buffers (renamed away by unroll-2) ----
    ka0 = kn0; ka1 = kn1;
#pragma unroll
    for (int cs=0;cs<4;++cs){
      vc[cs][0] = vn[cs][0];
      vc[cs][1] = vn[cs][1];
    }
  }

  // ---- l reduction ----
#pragma unroll
  for (int s=0;s<4;++s){
    lpart[s] += __shfl_xor(lpart[s], 16, 64);
    lpart[s] += __shfl_xor(lpart[s], 32, 64);
  }
  __syncthreads();
  if (q == 0){
#pragma unroll
    for (int s=0;s<4;++s) lsum[w][s*16 + iq] = lpart[s];
  }
  __syncthreads();
  float linv[4];
#pragma unroll
  for (int s=0;s<4;++s){
    const int i = s*16 + iq;
    linv[s] = 1.0f / (lsum[0][i] + lsum[1][i] + lsum[2][i] + lsum[3][i]);
  }

  const float gam = gamma[0];
#pragma unroll
  for (int cs=0;cs<4;++cs){
#pragma unroll
    for (int s=0;s<4;++s){
      const int cb = ch + w*64 + cs*16 + q*4;
      const int i  = i0 + s*16 + iq;
#pragma unroll
      for (int r=0;r<4;++r){
        const size_t idx = ((size_t)b*CC + cb + r)*NN + i;
        out[idx] = fmaf(gam, acc[cs][s][r]*linv[s], x[idx]);
      }
    }
  }
}

extern "C" void kernel_launch(void* const* d_in, const int* in_sizes, int n_in,
                              void* d_out, int out_size, void* d_ws, size_t ws_size,
                              hipStream_t stream){
  const float* x     = (const float*)d_in[0];
  const float* Wq    = (const float*)d_in[1];
  const float* bq    = (const float*)d_in[2];
  const float* Wk    = (const float*)d_in[3];
  const float* bk    = (const float*)d_in[4];
  const float* Wv    = (const float*)d_in[5];
  const float* bv    = (const float*)d_in[6];
  const float* gamma = (const float*)d_in[7];
  float* out = (float*)d_out;

  // workspace: xT bf16 [8][4096][512] 33.6MB; Qbf/Kbf bf16 [8][4096][64] 4.2MB each;
  // Vbf bf16 [8][512][4096] 33.6MB; Wqkbf [128][512] 128KB; Wvbf [512][512] 512KB. ~76 MB
  short* xTbf = (short*)d_ws;
  short* Qbf  = xTbf + (size_t)BB*NN*CC;
  short* Kbf  = Qbf  + (size_t)BB*NN*CQ;
  short* Vbf  = Kbf  + (size_t)BB*NN*CQ;
  short* Wqkbf= Vbf  + (size_t)BB*CC*NN;
  short* Wvbf = Wqkbf + (size_t)2*CQ*CC;

  cvt_w_kernel<<<dim3(CC*CC/256), 256, 0, stream>>>(Wq, Wk, Wv, Wqkbf, Wvbf);
  cvt_x_kernel<<<dim3(NN/64, CC/64, BB), 256, 0, stream>>>(x, xTbf);
  proj_qk_mfma<<<dim3(NN/128, 1, BB), 256, 0, stream>>>(xTbf, Wqkbf, bq, bk, Qbf, Kbf);
  proj_v_mfma<<<dim3(NN/64, CC/128, BB), 256, 0, stream>>>(xTbf, Wvbf, bv, Vbf);
  attn_mfma_kernel<<<dim3(BB*NN*2/MQ), 256, 0, stream>>>(Qbf, Kbf, Vbf, x, gamma, out);
}